// Round 6
// baseline (98.179 us; speedup 1.0000x reference)
//
#include <hip/hip_runtime.h>
#include <hip/hip_bf16.h>

typedef __attribute__((ext_vector_type(8))) short bf16x8;
typedef __attribute__((ext_vector_type(4))) float f32x4;

#define B_ROWS 8192
#define FDIM 128
#define BN 64            // cols per tile
#define NT 8             // tiles per block -> 512 cols per chunk
#define NCHUNK 16        // 8192 / 512

#define LOG2E 1.4426950408889634f

// ---------------- Kernel A: normalize; z1n scaled by log2(e); pos[i] exact ----------------
__global__ __launch_bounds__(256) void simclr_norm(const float* __restrict__ z1,
                                                   const float* __restrict__ z2,
                                                   __hip_bfloat16* __restrict__ z1n,
                                                   __hip_bfloat16* __restrict__ z2n,
                                                   float* __restrict__ pos) {
    int row  = (blockIdx.x * 256 + threadIdx.x) >> 6;   // one wave per row
    int lane = threadIdx.x & 63;
    int c = lane * 2;
    const float2 v1 = *(const float2*)(z1 + row * FDIM + c);
    const float2 v2 = *(const float2*)(z2 + row * FDIM + c);
    float s1 = v1.x * v1.x + v1.y * v1.y;
    float s2 = v2.x * v2.x + v2.y * v2.y;
    for (int m = 32; m > 0; m >>= 1) { s1 += __shfl_xor(s1, m); s2 += __shfl_xor(s2, m); }
    float inv1 = 1.0f / fmaxf(sqrtf(s1), 1e-12f);
    float inv2 = 1.0f / fmaxf(sqrtf(s2), 1e-12f);
    float a0 = v1.x * inv1, a1 = v1.y * inv1;
    float b0 = v2.x * inv2, b1 = v2.y * inv2;
    // S' = (log2e * z1n) . z2n  ->  2^S' == e^S in the row-sum
    z1n[row * FDIM + c]     = __float2bfloat16(a0 * LOG2E);
    z1n[row * FDIM + c + 1] = __float2bfloat16(a1 * LOG2E);
    z2n[row * FDIM + c]     = __float2bfloat16(b0);
    z2n[row * FDIM + c + 1] = __float2bfloat16(b1);
    float p = a0 * b0 + a1 * b1;                        // unscaled positive logit
    for (int m = 32; m > 0; m >>= 1) p += __shfl_xor(p, m);
    if (lane == 0) pos[row] = p;
}

// ---------------- Kernel B: barrier-free row-panel GEMM + exp2 + row-sum ----------------
// 256 threads / 4 independent waves (NO LDS, NO barriers). Each wave: 32 rows
// (in regs) x 512 cols, looping 8 tiles of 64 cols. B fragments loaded
// global->VGPR: the 16KB/tile B slice is L1-resident (z2n is L2-resident),
// and barrier-free waves let exp/VALU epilogue overlap other waves' MFMA.
// Zero-C trick on kk=0 avoids per-tile accumulator zero-init.
__global__ __launch_bounds__(256) void simclr_gemm(const __hip_bfloat16* __restrict__ z1n,
                                                   const __hip_bfloat16* __restrict__ z2n,
                                                   float* __restrict__ rsPart) {
    const int tid = threadIdx.x;
    const int wid = tid >> 6, lane = tid & 63;
    const int lq = lane >> 4, lr = lane & 15;
    const int rowBase = blockIdx.y * 128 + wid * 32;    // wave's 32 rows
    const int colBase = blockIdx.x * (NT * BN);

    const unsigned short* g1 = (const unsigned short*)z1n;
    const unsigned short* g2 = (const unsigned short*)z2n;

    // A fragments -> registers (once): 32 rows x 128 k per wave
    bf16x8 a[2][4];
#pragma unroll
    for (int m = 0; m < 2; ++m) {
        const unsigned short* rp = g1 + (size_t)(rowBase + m * 16 + lr) * FDIM + lq * 8;
#pragma unroll
        for (int kk = 0; kk < 4; ++kk)
            a[m][kk] = *(const bf16x8*)(rp + kk * 32);
    }

    // per-lane B base: row (colBase + n*16 + lr), k-slot lq*8
    const unsigned short* bb = g2 + (size_t)(colBase + lr) * FDIM + lq * 8;

    float rowsum[2][4] = {};
    const f32x4 z4 = {0.0f, 0.0f, 0.0f, 0.0f};

    // prefetch tile 0, kk=0
    bf16x8 bn[4];
#pragma unroll
    for (int n = 0; n < 4; ++n)
        bn[n] = *(const bf16x8*)(bb + (size_t)(n * 16) * FDIM);

#pragma unroll
    for (int t = 0; t < NT; ++t) {
        const unsigned short* bt = bb + (size_t)(t * BN) * FDIM;
        f32x4 acc[2][4];
        // kk = 0 with zero C (no accumulator init)
#pragma unroll
        for (int m = 0; m < 2; ++m)
#pragma unroll
            for (int n = 0; n < 4; ++n)
                acc[m][n] = __builtin_amdgcn_mfma_f32_16x16x32_bf16(a[m][0], bn[n], z4, 0, 0, 0);
#pragma unroll
        for (int kk = 1; kk < 4; ++kk) {
            bf16x8 b[4];
#pragma unroll
            for (int n = 0; n < 4; ++n)
                b[n] = *(const bf16x8*)(bt + (size_t)(n * 16) * FDIM + kk * 32);
#pragma unroll
            for (int m = 0; m < 2; ++m)
#pragma unroll
                for (int n = 0; n < 4; ++n)
                    acc[m][n] = __builtin_amdgcn_mfma_f32_16x16x32_bf16(a[m][kk], b[n], acc[m][n], 0, 0, 0);
        }
        // issue next tile's kk=0 loads BEFORE the epilogue so exp/add hides latency
        if (t + 1 < NT) {
            const unsigned short* btn = bb + (size_t)((t + 1) * BN) * FDIM;
#pragma unroll
            for (int n = 0; n < 4; ++n)
                bn[n] = *(const bf16x8*)(btn + (size_t)(n * 16) * FDIM);
        }
        // epilogue: rows m*16 + lq*4 + r; cols n*16 + lr. 2^acc == e^S.
#pragma unroll
        for (int m = 0; m < 2; ++m)
#pragma unroll
            for (int r = 0; r < 4; ++r)
                rowsum[m][r] += exp2f(acc[m][0][r]) + exp2f(acc[m][1][r]) +
                                exp2f(acc[m][2][r]) + exp2f(acc[m][3][r]);
    }

    // reduce across the 16 col-lanes; one plain store per row (no atomics)
#pragma unroll
    for (int m = 0; m < 2; ++m)
#pragma unroll
        for (int r = 0; r < 4; ++r) {
            float s = rowsum[m][r];
            s += __shfl_xor(s, 1); s += __shfl_xor(s, 2);
            s += __shfl_xor(s, 4); s += __shfl_xor(s, 8);
            if (lr == 0)
                rsPart[blockIdx.x * B_ROWS + rowBase + m * 16 + lq * 4 + r] = s;
        }
}

// ---------------- Kernel C: loss = mean(log(rowsum) - pos) ----------------
__global__ __launch_bounds__(256) void simclr_finish(const float* __restrict__ rsPart,
                                                     const float* __restrict__ pos,
                                                     float* __restrict__ out) {
    __shared__ float red[4];
    int i = blockIdx.x * 256 + threadIdx.x;   // one thread per row, 32 blocks
    float R = 0.0f;
#pragma unroll
    for (int c = 0; c < NCHUNK; ++c) R += rsPart[c * B_ROWS + i];
    float s = logf(R) - pos[i];
    for (int m = 32; m > 0; m >>= 1) s += __shfl_xor(s, m);
    if ((threadIdx.x & 63) == 0) red[threadIdx.x >> 6] = s;
    __syncthreads();
    if (threadIdx.x == 0) {
        float v = (red[0] + red[1]) + (red[2] + red[3]);
        atomicAdd(out, v * (1.0f / (float)B_ROWS));
    }
}

extern "C" void kernel_launch(void* const* d_in, const int* in_sizes, int n_in,
                              void* d_out, int out_size, void* d_ws, size_t ws_size,
                              hipStream_t stream) {
    const float* z1 = (const float*)d_in[0];
    const float* z2 = (const float*)d_in[1];
    float* out = (float*)d_out;
    char* ws = (char*)d_ws;

    __hip_bfloat16* z1n = (__hip_bfloat16*)ws;                       // 2 MB
    __hip_bfloat16* z2n = (__hip_bfloat16*)(ws + 2097152);           // 2 MB
    float* pos          = (float*)(ws + 4194304);                    // 32 KB
    float* rsPart       = (float*)(ws + 4194304 + 32768);            // 512 KB

    hipMemsetAsync(out, 0, sizeof(float), stream);
    simclr_norm<<<B_ROWS / 4, 256, 0, stream>>>(z1, z2, z1n, z2n, pos);
    simclr_gemm<<<dim3(NCHUNK, 64), 256, 0, stream>>>(z1n, z2n, rsPart);
    simclr_finish<<<B_ROWS / 256, 256, 0, stream>>>(rsPart, pos, out);
}

// Round 7
// 49.779 us; speedup vs baseline: 1.9723x; 1.9723x over previous
//
#include <hip/hip_runtime.h>
#include <hip/hip_bf16.h>

typedef __attribute__((ext_vector_type(8))) short bf16x8;
typedef __attribute__((ext_vector_type(4))) float f32x4;

#define B_ROWS 8192
#define FDIM 128
#define NT_TILES 16      // 32-col tiles per wave -> 512 cols per chunk
#define NCHUNK 16        // 8192 / 512

#define GLOAD_LDS(gp, lp) __builtin_amdgcn_global_load_lds( \
    (const __attribute__((address_space(1))) unsigned*)(gp), \
    (__attribute__((address_space(3))) unsigned*)(lp), 16, 0, 0)

#define LOG2E 1.4426950408889634f

// ---------------- Kernel A: normalize; z1n scaled by log2(e); pos[i] exact ----------------
__global__ __launch_bounds__(256) void simclr_norm(const float* __restrict__ z1,
                                                   const float* __restrict__ z2,
                                                   __hip_bfloat16* __restrict__ z1n,
                                                   __hip_bfloat16* __restrict__ z2n,
                                                   float* __restrict__ pos) {
    int row  = (blockIdx.x * 256 + threadIdx.x) >> 6;   // one wave per row
    int lane = threadIdx.x & 63;
    int c = lane * 2;
    const float2 v1 = *(const float2*)(z1 + row * FDIM + c);
    const float2 v2 = *(const float2*)(z2 + row * FDIM + c);
    float s1 = v1.x * v1.x + v1.y * v1.y;
    float s2 = v2.x * v2.x + v2.y * v2.y;
    for (int m = 32; m > 0; m >>= 1) { s1 += __shfl_xor(s1, m); s2 += __shfl_xor(s2, m); }
    float inv1 = 1.0f / fmaxf(sqrtf(s1), 1e-12f);
    float inv2 = 1.0f / fmaxf(sqrtf(s2), 1e-12f);
    float a0 = v1.x * inv1, a1 = v1.y * inv1;
    float b0 = v2.x * inv2, b1 = v2.y * inv2;
    // S' = (log2e * z1n) . z2n  ->  2^S' == e^S in the row-sum
    z1n[row * FDIM + c]     = __float2bfloat16(a0 * LOG2E);
    z1n[row * FDIM + c + 1] = __float2bfloat16(a1 * LOG2E);
    z2n[row * FDIM + c]     = __float2bfloat16(b0);
    z2n[row * FDIM + c + 1] = __float2bfloat16(b1);
    float p = a0 * b0 + a1 * b1;                        // unscaled positive logit
    for (int m = 32; m > 0; m >>= 1) p += __shfl_xor(p, m);
    if (lane == 0) pos[row] = p;
}

// ---------------- Kernel B: barrier-FREE wave-private-LDS GEMM + exp2 + row-sum ----------------
// 256 threads / 4 fully independent waves. Wave = 64 rows (A in regs, a[4][4])
// x 512 cols, iterated as 16 tiles of 32 cols. Each wave stages its own B
// slice (32 cols x 128 K = 8 KB) into its own 2x8KB LDS double-buffer via
// async global_load_lds, and waits with its own counted s_waitcnt vmcnt(8)
// (next tile's 8 loads stay in flight) - NO __syncthreads anywhere, so the
// 8 resident waves/CU overlap MFMA / exp / staging phases freely.
// XOR swizzle (verified rounds 1-5): stage with pre-swizzled global source,
// read with byte ^ ((row&7)<<4) -> 2-way bank access (free).
__global__ __launch_bounds__(256) void simclr_gemm(const __hip_bfloat16* __restrict__ z1n,
                                                   const __hip_bfloat16* __restrict__ z2n,
                                                   float* __restrict__ rsPart) {
    __shared__ unsigned char smem[65536];   // 4 waves x 2 bufs x 8 KB, wave-private
    const int tid = threadIdx.x;
    const int wid = tid >> 6, lane = tid & 63;
    const int lq = lane >> 4, lr = lane & 15;
    const int rowBase = blockIdx.y * 256 + wid * 64;   // wave's 64 rows
    const int colBase = blockIdx.x * (NT_TILES * 32);  // chunk of 512 cols
    unsigned char* myLds = smem + wid * 16384;

    const unsigned short* g1 = (const unsigned short*)z1n;
    const unsigned short* g2 = (const unsigned short*)z2n;

    // pre-swizzled per-lane global B sources (instr j covers rows j*4+lq;
    // (row&7) = (j&1)*4 + lq, so two bases indexed by j parity)
    const unsigned short* bsrc0 = g2 + (size_t)(colBase + lq) * FDIM + (lr ^ lq) * 8;
    const unsigned short* bsrc1 = g2 + (size_t)(colBase + lq) * FDIM + (lr ^ (4 + lq)) * 8;

    // stage tile t (32 B-rows) into buffer `buf`: 8 x global_load_lds(16B)
#define STAGE(t, buf) do {                                                        \
        _Pragma("unroll")                                                         \
        for (int j = 0; j < 8; ++j) {                                             \
            const unsigned short* gp = ((j & 1) ? bsrc1 : bsrc0)                  \
                                       + (size_t)((t) * 32 + j * 4) * FDIM;       \
            GLOAD_LDS(gp, myLds + (buf) * 8192 + j * 1024);                       \
        }                                                                         \
    } while (0)

    STAGE(0, 0);

    // A fragments -> registers (once): wave's 64 rows x 128 k
    bf16x8 a[4][4];
#pragma unroll
    for (int m = 0; m < 4; ++m) {
        const unsigned short* rp = g1 + (size_t)(rowBase + m * 16 + lr) * FDIM + lq * 8;
#pragma unroll
        for (int kk = 0; kk < 4; ++kk)
            a[m][kk] = *(const bf16x8*)(rp + kk * 32);
    }

    float rowsum[4][4] = {};
    const f32x4 z4 = {0.0f, 0.0f, 0.0f, 0.0f};

    for (int t = 0; t < NT_TILES; ++t) {
        const int cur = t & 1;
        if (t + 1 < NT_TILES) {
            STAGE(t + 1, cur ^ 1);
            // wait until only the 8 just-issued (tile t+1) loads remain ->
            // tile t's data is in LDS; t+1 stays in flight under compute.
            asm volatile("s_waitcnt vmcnt(8)" ::: "memory");
        } else {
            asm volatile("s_waitcnt vmcnt(0)" ::: "memory");
        }

        const unsigned char* bp = myLds + cur * 8192;
        f32x4 acc[4][2];
        // kk = 0 with zero C (skips per-tile accumulator init)
        {
            bf16x8 b0 = *(const bf16x8*)(bp + lr * 256 + ((lq * 16) ^ ((lr & 7) << 4)));
            bf16x8 b1 = *(const bf16x8*)(bp + (16 + lr) * 256 + ((lq * 16) ^ ((lr & 7) << 4)));
#pragma unroll
            for (int m = 0; m < 4; ++m) {
                acc[m][0] = __builtin_amdgcn_mfma_f32_16x16x32_bf16(a[m][0], b0, z4, 0, 0, 0);
                acc[m][1] = __builtin_amdgcn_mfma_f32_16x16x32_bf16(a[m][0], b1, z4, 0, 0, 0);
            }
        }
#pragma unroll
        for (int kk = 1; kk < 4; ++kk) {
            bf16x8 b0 = *(const bf16x8*)(bp + lr * 256 + ((kk * 64 + lq * 16) ^ ((lr & 7) << 4)));
            bf16x8 b1 = *(const bf16x8*)(bp + (16 + lr) * 256 + ((kk * 64 + lq * 16) ^ ((lr & 7) << 4)));
#pragma unroll
            for (int m = 0; m < 4; ++m) {
                acc[m][0] = __builtin_amdgcn_mfma_f32_16x16x32_bf16(a[m][kk], b0, acc[m][0], 0, 0, 0);
                acc[m][1] = __builtin_amdgcn_mfma_f32_16x16x32_bf16(a[m][kk], b1, acc[m][1], 0, 0, 0);
            }
        }
        // epilogue: rows m*16 + lq*4 + r; cols n*16 + lr. 2^acc == e^S.
#pragma unroll
        for (int m = 0; m < 4; ++m)
#pragma unroll
            for (int r = 0; r < 4; ++r)
                rowsum[m][r] += exp2f(acc[m][0][r]) + exp2f(acc[m][1][r]);
    }
#undef STAGE

    // reduce across the 16 col-lanes; one plain store per row (no atomics)
#pragma unroll
    for (int m = 0; m < 4; ++m)
#pragma unroll
        for (int r = 0; r < 4; ++r) {
            float s = rowsum[m][r];
            s += __shfl_xor(s, 1); s += __shfl_xor(s, 2);
            s += __shfl_xor(s, 4); s += __shfl_xor(s, 8);
            if (lr == 0)
                rsPart[blockIdx.x * B_ROWS + rowBase + m * 16 + lq * 4 + r] = s;
        }
}

// ---------------- Kernel C: loss = mean(log(rowsum) - pos) ----------------
__global__ __launch_bounds__(256) void simclr_finish(const float* __restrict__ rsPart,
                                                     const float* __restrict__ pos,
                                                     float* __restrict__ out) {
    __shared__ float red[4];
    int i = blockIdx.x * 256 + threadIdx.x;   // one thread per row, 32 blocks
    float R = 0.0f;
#pragma unroll
    for (int c = 0; c < NCHUNK; ++c) R += rsPart[c * B_ROWS + i];
    float s = logf(R) - pos[i];
    for (int m = 32; m > 0; m >>= 1) s += __shfl_xor(s, m);
    if ((threadIdx.x & 63) == 0) red[threadIdx.x >> 6] = s;
    __syncthreads();
    if (threadIdx.x == 0) {
        float v = (red[0] + red[1]) + (red[2] + red[3]);
        atomicAdd(out, v * (1.0f / (float)B_ROWS));
    }
}

extern "C" void kernel_launch(void* const* d_in, const int* in_sizes, int n_in,
                              void* d_out, int out_size, void* d_ws, size_t ws_size,
                              hipStream_t stream) {
    const float* z1 = (const float*)d_in[0];
    const float* z2 = (const float*)d_in[1];
    float* out = (float*)d_out;
    char* ws = (char*)d_ws;

    __hip_bfloat16* z1n = (__hip_bfloat16*)ws;                       // 2 MB
    __hip_bfloat16* z2n = (__hip_bfloat16*)(ws + 2097152);           // 2 MB
    float* pos          = (float*)(ws + 4194304);                    // 32 KB
    float* rsPart       = (float*)(ws + 4194304 + 32768);            // 512 KB

    hipMemsetAsync(out, 0, sizeof(float), stream);
    simclr_norm<<<B_ROWS / 4, 256, 0, stream>>>(z1, z2, z1n, z2n, pos);
    // blockIdx.x = col chunk (16), blockIdx.y = row group (32): 512 blocks,
    // 2 resident/CU (64KB LDS), one full residency round.
    simclr_gemm<<<dim3(NCHUNK, 32), 256, 0, stream>>>(z1n, z2n, rsPart);
    simclr_finish<<<B_ROWS / 256, 256, 0, stream>>>(rsPart, pos, out);
}